// Round 5
// baseline (364.438 us; speedup 1.0000x reference)
//
#include <hip/hip_runtime.h>
#include <hip/hip_bf16.h>

#define NUSERS 100000
#define NITEMS 50000
#define NN (NUSERS + NITEMS)      // 150000
#define NE 4000000
#define DIM 64
#define BQ 4096
#define NBIN ((NN + 255) >> 8)    // 586 bins of 256 rows
#define BINCAP 9216               // fixed slots/bin; mean w/ pads 7851, sigma ~90
#define EPB2 8192                 // edges per block in pass A (8/thread @ 1024)
#define PLANE_U16 ((NN + 1) * 32)         // u16 elems per 32-dim plane (incl sentinel)
#define PLANE_BYTES ((NN + 1) * 64)       // 9,600,064 B

typedef unsigned short u16;
typedef unsigned int u32;
typedef float v2f __attribute__((ext_vector_type(2)));
typedef unsigned u32x2 __attribute__((ext_vector_type(2)));

__device__ __forceinline__ float bf2f(u16 u) {
    return __uint_as_float(((unsigned)u) << 16);
}
__device__ __forceinline__ u16 f2bf(float f) {
    unsigned x = __float_as_uint(f);
    return (u16)((x + 0x7FFFu + ((x >> 16) & 1u)) >> 16);   // RNE
}
// unpack uint4 (8 bf16) into 4 packed-f32 accumulates (v_pk_add_f32)
__device__ __forceinline__ void add8p(v2f* acc2, uint4 u) {
    acc2[0] += (v2f){__uint_as_float(u.x << 16), __uint_as_float(u.x & 0xffff0000u)};
    acc2[1] += (v2f){__uint_as_float(u.y << 16), __uint_as_float(u.y & 0xffff0000u)};
    acc2[2] += (v2f){__uint_as_float(u.z << 16), __uint_as_float(u.z & 0xffff0000u)};
    acc2[3] += (v2f){__uint_as_float(u.w << 16), __uint_as_float(u.w & 0xffff0000u)};
}

// ---- cross-lane adds on the VALU pipe (no ds/lgkm chains) ----
// rotations by multiples of 4 within 16-lane DPP rows preserve lane&3 (dg)
#if __has_builtin(__builtin_amdgcn_update_dpp)
__device__ __forceinline__ float xadd4(float x) {
    int y = __builtin_amdgcn_update_dpp(0, __float_as_int(x), 0x124, 0xF, 0xF, true);
    return x + __int_as_float(y);     // row_ror:4
}
__device__ __forceinline__ float xadd8(float x) {
    int y = __builtin_amdgcn_update_dpp(0, __float_as_int(x), 0x128, 0xF, 0xF, true);
    return x + __int_as_float(y);     // row_ror:8
}
#else
__device__ __forceinline__ float xadd4(float x) { return x + __shfl_xor(x, 4, 64); }
__device__ __forceinline__ float xadd8(float x) { return x + __shfl_xor(x, 8, 64); }
#endif
#if __has_builtin(__builtin_amdgcn_permlane16_swap)
__device__ __forceinline__ float xadd16(float x) {
    u32x2 r = __builtin_amdgcn_permlane16_swap(__float_as_uint(x), __float_as_uint(x),
                                               false, false);
    return __uint_as_float(r.x) + __uint_as_float(r.y);
}
#else
__device__ __forceinline__ float xadd16(float x) { return x + __shfl_xor(x, 16, 64); }
#endif

#if __has_builtin(__builtin_amdgcn_sched_barrier)
#define SCHED_FENCE() __builtin_amdgcn_sched_barrier(0)
#else
#define SCHED_FENCE()
#endif

// reduce over 8 eslots (lane bits 2,3,4); rotations sum bits 2,3; swap sums bit 4
__device__ __forceinline__ void reduce_es(v2f* acc2) {
#pragma unroll
    for (int j = 0; j < 4; ++j) { acc2[j].x = xadd4(acc2[j].x);  acc2[j].y = xadd4(acc2[j].y);  }
#pragma unroll
    for (int j = 0; j < 4; ++j) { acc2[j].x = xadd8(acc2[j].x);  acc2[j].y = xadd8(acc2[j].y);  }
#pragma unroll
    for (int j = 0; j < 4; ++j) { acc2[j].x = xadd16(acc2[j].x); acc2[j].y = xadd16(acc2[j].y); }
}

// reduce over 4 eslots (lane bits 3,4) — old layout, used by k_spmm_out2
__device__ __forceinline__ void reduce_half(v2f* acc2) {
#pragma unroll
    for (int j = 0; j < 4; ++j) { acc2[j].x = xadd8(acc2[j].x);  acc2[j].y = xadd8(acc2[j].y);  }
#pragma unroll
    for (int j = 0; j < 4; ++j) { acc2[j].x = xadd16(acc2[j].x); acc2[j].y = xadd16(acc2[j].y); }
}

// plane-layout batch: 4 gathers cover slots [s0, s0+32) of this half's row
// (8 eslots x 4 g); invalid slots -> sentinel row NN (zeros, cache-hot)
__device__ __forceinline__ void batchH(const int* __restrict__ col_s, int start,
                                       int s0, int lim, int eslot,
                                       const char* __restrict__ base2, v2f* acc2) {
    int cg[4];
#pragma unroll
    for (int g = 0; g < 4; ++g) {
        int slot = s0 + (g << 3) + eslot;
        int c = col_s[start + slot];
        cg[g] = (slot < lim) ? c : NN;
    }
    uint4 v[4];
#pragma unroll
    for (int g = 0; g < 4; ++g)
        v[g] = *(const uint4*)(base2 + (((u32)cg[g]) << 6));
    SCHED_FENCE();
#pragma unroll
    for (int g = 0; g < 4; ++g) add8p(acc2, v[g]);
}

// old-layout batch for k_spmm_out2 (4 eslots x 8 dg), plane-split source
__device__ __forceinline__ void batch8q(const int* __restrict__ col_s, int start,
                                        int s0, int lim, int eslot,
                                        const char* __restrict__ base2, v2f* acc2) {
    int cg[8];
#pragma unroll
    for (int g = 0; g < 8; ++g) {
        int slot = s0 + (g << 2) + eslot;
        int c = col_s[start + slot];
        cg[g] = (slot < lim) ? c : NN;
    }
    uint4 v[8];
#pragma unroll
    for (int g = 0; g < 8; ++g)
        v[g] = *(const uint4*)(base2 + (((u32)cg[g]) << 6));
    SCHED_FENCE();
#pragma unroll
    for (int g = 0; g < 8; ++g) add8p(acc2, v[g]);
}

// ---------------- SpMM, one 32-dim plane per dispatch ----------------
// t_{k+1}[r][dims of PASS] = (1/deg[r]) * sum_{c in N(r)} t_k[c][dims of PASS]
// 2 rows per wave; per row: 8 eslots x 4 dg (16 B/lane over the 64-B plane-row)
template<int PASS, bool MASKED>
__global__ void __launch_bounds__(256) k_spmmH(
        const int2* __restrict__ meta2, const int* __restrict__ col_s,
        const u16* __restrict__ in, u16* __restrict__ out,
        const unsigned char* __restrict__ mask) {
    int wid = (blockIdx.x * blockDim.x + threadIdx.x) >> 6;
    int lane = threadIdx.x & 63;
    int half = lane >> 5;
    int eslot = (lane >> 2) & 7;
    int dg = lane & 3;
    int r = (wid << 1) + half;            // grid sized so r < NN always
    int2 mv = meta2[r];
    int start = mv.x, n = mv.y;
    int m = MASKED ? (int)mask[r] : 1;
    int n8 = (n + 7) & ~7;
    int lim = m ? n8 : 0;
    if (MASKED && !__any(lim > 0)) return;
    const char* base2 = (const char*)in + (u32)PASS * (u32)PLANE_BYTES + (dg << 4);

    v2f acc2[4] = {(v2f)0.f, (v2f)0.f, (v2f)0.f, (v2f)0.f};
    batchH(col_s, start, 0, lim, eslot, base2, acc2);
    if (__any(lim > 32))
        batchH(col_s, start, 32, lim, eslot, base2, acc2);
    if (__any(lim > 64)) {                // safety net; ~never with this input
        for (int i = 64 + eslot; i < lim; i += 8) {
            int c = col_s[start + i];
            uint4 u = *(const uint4*)(base2 + (((u32)c) << 6));
            add8p(acc2, u);
        }
    }
    reduce_es(acc2);
    if (eslot == 0 && m) {
        float sc = (n > 0) ? (1.0f / (float)n) : 0.0f;   // dis[r]^2
        v2f vs = {sc, sc};
        u32 p[4];
#pragma unroll
        for (int j = 0; j < 4; ++j) {
            v2f t = acc2[j] * vs;
            __hip_bfloat162 h = __float22bfloat162_rn(make_float2(t.x, t.y));
            p[j] = *(u32*)&h;
        }
        ((uint4*)(out + (size_t)PASS * PLANE_U16))[(size_t)r * 4 + dg] =
            make_uint4(p[0], p[1], p[2], p[3]);
    }
}

// hop-3 fused: 2 query slots per wave; out = (out + dis[r]*sum t2[c]) * 0.25
// reads BOTH planes (dg<4 -> plane0, dg>=4 -> plane1); small traffic, unsplit
__global__ void __launch_bounds__(256) k_spmm_out2(
        const int2* __restrict__ meta2, const int* __restrict__ col_s,
        const u16* __restrict__ in, const int* __restrict__ uid,
        const int* __restrict__ iid, float* __restrict__ out) {
    int wid = (blockIdx.x * blockDim.x + threadIdx.x) >> 6;
    int lane = threadIdx.x & 63;
    int half = lane >> 5;
    int eslot = (lane >> 3) & 3;
    int dg = lane & 7;
    int q = (wid << 1) + half;            // grid sized so q < 2*BQ always
    int b, r, off;
    if (q < BQ) { b = q; r = uid[q]; off = 0; }
    else { b = q - BQ; r = NUSERS + iid[q - BQ]; off = DIM; }
    int2 mv = meta2[r];
    int start = mv.x, n = mv.y;
    int n8 = (n + 7) & ~7;
    const char* base2 = (const char*)in + (u32)(dg >> 2) * (u32)PLANE_BYTES
                      + ((dg & 3) << 4);

    v2f acc2[4] = {(v2f)0.f, (v2f)0.f, (v2f)0.f, (v2f)0.f};
    batch8q(col_s, start, 0, n8, eslot, base2, acc2);
    if (__any(n8 > 32))
        batch8q(col_s, start, 32, n8, eslot, base2, acc2);
    if (__any(n8 > 64)) {
        for (int i = 64 + eslot; i < n8; i += 4) {
            int c = col_s[start + i];
            uint4 u = *(const uint4*)(base2 + (((u32)c) << 6));
            add8p(acc2, u);
        }
    }
    reduce_half(acc2);
    if (eslot == 0) {
        float dr = (n > 0) ? (1.0f / sqrtf((float)n)) : 0.0f;   // dis[r]
        float* o = out + (size_t)b * (2 * DIM) + off + dg * 8;
#pragma unroll
        for (int j = 0; j < 4; ++j) {
            o[2 * j]     = (o[2 * j]     + dr * acc2[j].x) * 0.25f;
            o[2 * j + 1] = (o[2 * j + 1] + dr * acc2[j].y) * 0.25f;
        }
    }
}

// ---------------- init: bin cursors, m2 mask, sentinel rows ----------------
__global__ void k_init(int* __restrict__ bin_cur, u32* __restrict__ m2w,
                       u16* __restrict__ ea, u16* __restrict__ eb) {
    int t = blockIdx.x * blockDim.x + threadIdx.x;
    if (t < NBIN) bin_cur[t] = t * BINCAP;
    if (t < 37504) m2w[t] = 0;                 // zero 150016 bytes of m2
    if (t < 16) {                              // zero sentinel row NN, both planes/tables
        ((u32*)(ea + (size_t)NN * 32))[t] = 0;
        ((u32*)(ea + (size_t)PLANE_U16 + (size_t)NN * 32))[t] = 0;
        ((u32*)(eb + (size_t)NN * 32))[t] = 0;
        ((u32*)(eb + (size_t)PLANE_U16 + (size_t)NN * 32))[t] = 0;
    }
}

// ---------------- Pass A: block-local counting sort, coalesced flush -------
__global__ void __launch_bounds__(1024) k_binA2(
        const int* __restrict__ row, const int* __restrict__ col,
        int* __restrict__ bin_cur, u32* __restrict__ pairs, int E) {
    __shared__ u32 stage[EPB2];            // 32 KB
    __shared__ int hist[NBIN];
    __shared__ int base_l[NBIN];
    __shared__ int cbase[NBIN];
    __shared__ int lcur[NBIN];
    __shared__ int s[1024];
    int t = threadIdx.x;
    int base = blockIdx.x * EPB2;
    int lim = min(E - base, EPB2);

    if (t < NBIN) hist[t] = 0;
    __syncthreads();

    for (int i = t; i < lim; i += 1024)
        atomicAdd(&hist[row[base + i] >> 8], 1);
    __syncthreads();

    int v = (t < NBIN) ? hist[t] : 0;
    s[t] = v;
    __syncthreads();
    for (int off = 1; off < 1024; off <<= 1) {
        int x = (t >= off) ? s[t - off] : 0;
        __syncthreads();
        s[t] += x;
        __syncthreads();
    }
    if (t < NBIN) {
        int excl = s[t] - v;
        base_l[t] = excl;
        lcur[t] = excl;
        cbase[t] = (v > 0) ? atomicAdd(&bin_cur[t], v) : 0;
    }
    __syncthreads();

    for (int i = t; i < lim; i += 1024) {
        int r = row[base + i];
        int c = col[base + i];
        int pos = atomicAdd(&lcur[r >> 8], 1);
        stage[pos] = ((u32)(r & 255) << 24) | (u32)c;
    }
    __syncthreads();

    int wv = t >> 6;
    int lane = t & 63;
    for (int b = wv; b < NBIN; b += 16) {
        int h = hist[b];
        int lb = base_l[b];
        size_t gb = (size_t)cbase[b];
        for (int i = lane; i < h; i += 64)
            pairs[gb + i] = stage[lb + i];
    }
}

// ---------------- Pass B: per-bin row sort; derives rs/deg/meta2; pads to 8 ----
__global__ void __launch_bounds__(1024) k_binB(
        const u32* __restrict__ pairs, const int* __restrict__ bin_cur,
        int* __restrict__ col_s, int* __restrict__ rs, int* __restrict__ deg,
        int2* __restrict__ meta2) {
    __shared__ int cnt[256];
    __shared__ int pscan[256];
    __shared__ int cur[256];
    int b = blockIdx.x;
    int t = threadIdx.x;
    int base = b * BINCAP;
    int end = bin_cur[b];
    if (t < 256) cnt[t] = 0;
    __syncthreads();
    for (int i = base + t; i < end; i += 1024)
        atomicAdd(&cnt[pairs[i] >> 24], 1);
    __syncthreads();
    int v = (t < 256) ? cnt[t] : 0;
    int pv = (v + 7) & ~7;                    // row segment padded to multiple of 8
    if (t < 256) pscan[t] = pv;
    __syncthreads();
    for (int off = 1; off < 256; off <<= 1) {
        int x = (t >= off && t < 256) ? pscan[t - off] : 0;
        __syncthreads();
        if (t < 256) pscan[t] += x;
        __syncthreads();
    }
    if (t < 256) {
        int rowstart = base + pscan[t] - pv;
        int r = (b << 8) + t;
        if (r < NN) {
            rs[r] = rowstart;
            deg[r] = v;
            meta2[r] = make_int2(rowstart, v);
        }
        cur[t] = rowstart;
        for (int i = v; i < pv; ++i) col_s[rowstart + i] = NN;   // sentinel pads
    }
    __syncthreads();
    for (int i = base + t; i < end; i += 1024) {
        u32 p = pairs[i];
        int pos = atomicAdd(&cur[p >> 24], 1);
        col_s[pos] = (int)(p & 0x00FFFFFFu);
    }
}

// ---------------- t0 = dis ⊙ emb0, bf16, plane-split layout ----------------
__global__ void k_concat_t0(const float* __restrict__ u, const float* __restrict__ it,
                            const int* __restrict__ deg, u16* __restrict__ emb) {
    int i = blockIdx.x * blockDim.x + threadIdx.x;   // float4 index (4 dims), 16/row
    const int NU4 = NUSERS * DIM / 4;
    const int NT4 = NN * DIM / 4;
    if (i >= NT4) return;
    int row = i >> 4;
    int sub = i & 15;                 // 4-dim group within the row
    int d = deg[row];
    float sc = (d > 0) ? (1.0f / sqrtf((float)d)) : 0.0f;
    float4 v = (i < NU4) ? ((const float4*)u)[i] : ((const float4*)it)[i - NU4];
    ushort4 o;
    o.x = f2bf(sc * v.x); o.y = f2bf(sc * v.y);
    o.z = f2bf(sc * v.z); o.w = f2bf(sc * v.w);
    int plane = sub >> 3;             // dims 0..31 -> plane 0, 32..63 -> plane 1
    int po = sub & 7;                 // ushort4 slot within the 32-u16 plane-row
    ((ushort4*)(emb + (size_t)plane * PLANE_U16))[(size_t)row * 8 + po] = o;
}

// mark rows needed for hop-2 output: one wave per query row, lanes scatter
__global__ void k_mark(const int* __restrict__ uid, const int* __restrict__ iid,
                       const int* __restrict__ rs, const int* __restrict__ deg,
                       const int* __restrict__ col_s, unsigned char* __restrict__ m2) {
    int q = (blockIdx.x * blockDim.x + threadIdx.x) >> 6;
    if (q >= 2 * BQ) return;
    int lane = threadIdx.x & 63;
    int r = (q < BQ) ? uid[q] : (NUSERS + iid[q - BQ]);
    if (lane == 0) m2[r] = 1;
    int s = rs[r], n = deg[r];
    for (int i = lane; i < n; i += 64) m2[col_s[s + i]] = 1;
}

// ---------------- output gathers ----------------

__global__ void k_gather_init(const int* __restrict__ uid, const int* __restrict__ iid,
                              const float* __restrict__ u, const float* __restrict__ it,
                              float* __restrict__ out) {
    int t = blockIdx.x * blockDim.x + threadIdx.x;
    if (t >= BQ * DIM) return;
    int b = t >> 6;
    int d = t & 63;
    out[b * (2 * DIM) + d]       = u[(size_t)uid[b] * DIM + d];
    out[b * (2 * DIM) + DIM + d] = it[(size_t)iid[b] * DIM + d];
}

// out += sqrt(deg[r]) * t_k[r]   (emb_k = rdis ⊙ t_k), plane-split table
__global__ void k_gather_add(const int* __restrict__ uid, const int* __restrict__ iid,
                             const int* __restrict__ deg, const u16* __restrict__ emb,
                             float* __restrict__ out) {
    int t = blockIdx.x * blockDim.x + threadIdx.x;
    if (t >= BQ * DIM) return;
    int b = t >> 6;
    int d = t & 63;
    int ru = uid[b];
    int ri = NUSERS + iid[b];
    int du = deg[ru], di = deg[ri];
    float su = (du > 0) ? sqrtf((float)du) : 0.0f;
    float si = (di > 0) ? sqrtf((float)di) : 0.0f;
    size_t pb = (size_t)(d >> 5) * PLANE_U16;
    int dd = d & 31;
    int ou = b * (2 * DIM) + d;
    int oi = ou + DIM;
    out[ou] = out[ou] + su * bf2f(emb[pb + (size_t)ru * 32 + dd]);
    out[oi] = out[oi] + si * bf2f(emb[pb + (size_t)ri * 32 + dd]);
}

// ---------------- launch ----------------

extern "C" void kernel_launch(void* const* d_in, const int* in_sizes, int n_in,
                              void* d_out, int out_size, void* d_ws, size_t ws_size,
                              hipStream_t stream) {
    const float* users_emb = (const float*)d_in[0];
    const float* items_emb = (const float*)d_in[1];
    const int*   edge_row  = (const int*)d_in[2];
    const int*   edge_col  = (const int*)d_in[3];
    const int*   user_id   = (const int*)d_in[4];
    const int*   item_ids  = (const int*)d_in[5];
    float* out = (float*)d_out;

    char* ws = (char*)d_ws;
    // byte layout (ends ~90.3 MB):
    int*   deg_i   = (int*)  (ws + 0);          // 600 KB
    int*   rs      = (int*)  (ws + 655360);     // 600 KB
    int*   bin_cur = (int*)  (ws + 1310720);    // 2.4 KB
    unsigned char* m2 = (unsigned char*)(ws + 1400000);  // 150 KB
    int2*  meta2   = (int2*) (ws + 2097152);    // 1.2 MB
    int*   col_s   = (int*)  (ws + 4194304);    // 586*9216*4 = 21.6 MB
    u32*   pairs   = (u32*)  (ws + 29360128);   // 21.6 MB
    u16*   emb_a   = (u16*)  (ws + 54525952);   // 2 planes x 9.6 MB = 19.2 MB
    u16*   emb_b   = (u16*)  (ws + 75497472);   // 19.2 MB

    // init cursors + m2 + sentinel rows
    k_init<<<147, 256, 0, stream>>>(bin_cur, (u32*)m2, emb_a, emb_b);

    // binned CSR build (counting-sort pass A; pass B derives deg/rs/meta2)
    k_binA2<<<(NE + EPB2 - 1) / EPB2, 1024, 0, stream>>>(edge_row, edge_col, bin_cur,
                                                         pairs, NE);
    k_binB<<<NBIN, 1024, 0, stream>>>(pairs, bin_cur, col_s, rs, deg_i, meta2);

    // t0 table (bf16, dis-folded, plane-split)
    k_concat_t0<<<(NN * DIM / 4 + 255) / 256, 256, 0, stream>>>(users_emb, items_emb,
                                                                deg_i, emb_a);

    // layer-0 contribution (fp32 sources)
    k_gather_init<<<(BQ * DIM + 255) / 256, 256, 0, stream>>>(user_id, item_ids,
                                                              users_emb, items_emb, out);

    // mark rows whose hop-2 output is read (one wave per query row)
    k_mark<<<(2 * BQ + 3) / 4, 256, 0, stream>>>(user_id, item_ids, rs, deg_i, col_s, m2);

    // hops: 2 rows/wave, 4 waves/block -> NN/2/4 = 18750 blocks; one plane per
    // dispatch (sequential passes shrink the gather working set to 9.6 MB)
    // hop 1: full
    k_spmmH<0, false><<<18750, 256, 0, stream>>>(meta2, col_s, emb_a, emb_b,
                                                 (const unsigned char*)nullptr);
    k_spmmH<1, false><<<18750, 256, 0, stream>>>(meta2, col_s, emb_a, emb_b,
                                                 (const unsigned char*)nullptr);
    k_gather_add<<<(BQ * DIM + 255) / 256, 256, 0, stream>>>(user_id, item_ids, deg_i,
                                                             emb_b, out);
    // hop 2: masked
    k_spmmH<0, true><<<18750, 256, 0, stream>>>(meta2, col_s, emb_b, emb_a, m2);
    k_spmmH<1, true><<<18750, 256, 0, stream>>>(meta2, col_s, emb_b, emb_a, m2);
    k_gather_add<<<(BQ * DIM + 255) / 256, 256, 0, stream>>>(user_id, item_ids, deg_i,
                                                             emb_a, out);
    // hop 3: fused into output, fp32 accumulate, final /4 (2*BQ/2/4 = 1024 blocks)
    k_spmm_out2<<<1024, 256, 0, stream>>>(meta2, col_s, emb_a, user_id, item_ids, out);
}

// Round 6
// 298.647 us; speedup vs baseline: 1.2203x; 1.2203x over previous
//
#include <hip/hip_runtime.h>
#include <hip/hip_bf16.h>

#define NUSERS 100000
#define NITEMS 50000
#define NN (NUSERS + NITEMS)      // 150000
#define NE 4000000
#define DIM 64
#define BQ 4096
#define NBIN ((NN + 255) >> 8)    // 586 bins of 256 rows
#define BINCAP 9216               // fixed slots/bin; mean w/ pads 7851, sigma ~90
#define EPB2 12288                // edges per block in pass A (12/thread @ 1024)

typedef unsigned short u16;
typedef unsigned int u32;
typedef float v2f __attribute__((ext_vector_type(2)));
typedef unsigned u32x2 __attribute__((ext_vector_type(2)));

#if __has_builtin(__builtin_nontemporal_load)
#define NTLOAD(p) __builtin_nontemporal_load(p)
#else
#define NTLOAD(p) (*(p))
#endif

__device__ __forceinline__ float bf2f(u16 u) {
    return __uint_as_float(((unsigned)u) << 16);
}
__device__ __forceinline__ u16 f2bf(float f) {
    unsigned x = __float_as_uint(f);
    return (u16)((x + 0x7FFFu + ((x >> 16) & 1u)) >> 16);   // RNE
}
// unpack uint4 (8 bf16) into 4 packed-f32 accumulates (v_pk_add_f32)
__device__ __forceinline__ void add8p(v2f* acc2, uint4 u) {
    acc2[0] += (v2f){__uint_as_float(u.x << 16), __uint_as_float(u.x & 0xffff0000u)};
    acc2[1] += (v2f){__uint_as_float(u.y << 16), __uint_as_float(u.y & 0xffff0000u)};
    acc2[2] += (v2f){__uint_as_float(u.z << 16), __uint_as_float(u.z & 0xffff0000u)};
    acc2[3] += (v2f){__uint_as_float(u.w << 16), __uint_as_float(u.w & 0xffff0000u)};
}

// ---- cross-lane adds on the VALU pipe (no ds/lgkm chains) ----
// xadd8: sum over lane bit 3 (row_ror:8 within 16-lane DPP rows)
#if __has_builtin(__builtin_amdgcn_update_dpp)
__device__ __forceinline__ float xadd8(float x) {
    int y = __builtin_amdgcn_update_dpp(0, __float_as_int(x), 0x128, 0xF, 0xF, true);
    return x + __int_as_float(y);
}
#else
__device__ __forceinline__ float xadd8(float x) { return x + __shfl_xor(x, 8, 64); }
#endif
// xadd16: sum over lane bit 4 (stays within each 32-lane half)
#if __has_builtin(__builtin_amdgcn_permlane16_swap)
__device__ __forceinline__ float xadd16(float x) {
    u32x2 r = __builtin_amdgcn_permlane16_swap(__float_as_uint(x), __float_as_uint(x),
                                               false, false);
    return __uint_as_float(r.x) + __uint_as_float(r.y);
}
#else
__device__ __forceinline__ float xadd16(float x) { return x + __shfl_xor(x, 16, 64); }
#endif

#if __has_builtin(__builtin_amdgcn_sched_barrier)
#define SCHED_FENCE() __builtin_amdgcn_sched_barrier(0)
#else
#define SCHED_FENCE()
#endif

// reduce over the 4 edge slots of each 32-lane half (lane bits 3,4)
__device__ __forceinline__ void reduce_half(v2f* acc2) {
#pragma unroll
    for (int j = 0; j < 4; ++j) { acc2[j].x = xadd8(acc2[j].x);  acc2[j].y = xadd8(acc2[j].y);  }
#pragma unroll
    for (int j = 0; j < 4; ++j) { acc2[j].x = xadd16(acc2[j].x); acc2[j].y = xadd16(acc2[j].y); }
}

// one batch of 8 gathers covering slots [s0, s0+32) of this half's row;
// invalid slots -> sentinel row NN (zeros, cache-hot).
// col_s loads are nontemporal: 23 MB streamed once/hop, keep it out of L2.
__device__ __forceinline__ void batch8(const int* __restrict__ col_s, int start,
                                       int s0, int lim, int eslot,
                                       const char* __restrict__ base2, v2f* acc2) {
    int cg[8];
#pragma unroll
    for (int g = 0; g < 8; ++g) {
        int slot = s0 + (g << 2) + eslot;
        int c = NTLOAD(col_s + start + slot);
        cg[g] = (slot < lim) ? c : NN;
    }
    uint4 v[8];
#pragma unroll
    for (int g = 0; g < 8; ++g)
        v[g] = *(const uint4*)(base2 + (((u32)cg[g]) << 7));
    SCHED_FENCE();
#pragma unroll
    for (int g = 0; g < 8; ++g) add8p(acc2, v[g]);
}

// ---------------- SpMM: 2 rows per wave, 32 lanes (4 eslots x 8 dg) per row ----
// t_{k+1}[r] = (1/deg[r]) * sum_{c in N(r)} t_k[c]
template<bool MASKED>
__global__ void __launch_bounds__(256) k_spmm2(
        const int2* __restrict__ meta2, const int* __restrict__ col_s,
        const u16* __restrict__ in, u16* __restrict__ out,
        const unsigned char* __restrict__ mask) {
    int wid = (blockIdx.x * blockDim.x + threadIdx.x) >> 6;
    int lane = threadIdx.x & 63;
    int half = lane >> 5;
    int eslot = (lane >> 3) & 3;
    int dg = lane & 7;
    int r = (wid << 1) + half;            // grid sized so r < NN always
    int2 mv = meta2[r];
    int start = mv.x, n = mv.y;
    int m = MASKED ? (int)mask[r] : 1;
    int n8 = (n + 7) & ~7;
    int lim = m ? n8 : 0;
    if (MASKED && !__any(lim > 0)) return;
    const char* base2 = (const char*)in + (dg << 4);

    v2f acc2[4] = {(v2f)0.f, (v2f)0.f, (v2f)0.f, (v2f)0.f};
    batch8(col_s, start, 0, lim, eslot, base2, acc2);
    if (__any(lim > 32))
        batch8(col_s, start, 32, lim, eslot, base2, acc2);
    if (__any(lim > 64)) {                // safety net; ~never with this input
        for (int i = 64 + eslot; i < lim; i += 4) {
            int c = col_s[start + i];
            uint4 u = *(const uint4*)(base2 + (((u32)c) << 7));
            add8p(acc2, u);
        }
    }
    reduce_half(acc2);
    if (eslot == 0 && m) {
        float sc = (n > 0) ? (1.0f / (float)n) : 0.0f;   // dis[r]^2
        v2f vs = {sc, sc};
        u32 p[4];
#pragma unroll
        for (int j = 0; j < 4; ++j) {
            v2f t = acc2[j] * vs;
            __hip_bfloat162 h = __float22bfloat162_rn(make_float2(t.x, t.y));
            p[j] = *(u32*)&h;
        }
        ((uint4*)out)[(size_t)r * 8 + dg] = make_uint4(p[0], p[1], p[2], p[3]);
    }
}

// hop-3 fused: 2 query slots per wave; out = (out + dis[r]*sum t2[c]) * 0.25
__global__ void __launch_bounds__(256) k_spmm_out2(
        const int2* __restrict__ meta2, const int* __restrict__ col_s,
        const u16* __restrict__ in, const int* __restrict__ uid,
        const int* __restrict__ iid, float* __restrict__ out) {
    int wid = (blockIdx.x * blockDim.x + threadIdx.x) >> 6;
    int lane = threadIdx.x & 63;
    int half = lane >> 5;
    int eslot = (lane >> 3) & 3;
    int dg = lane & 7;
    int q = (wid << 1) + half;            // grid sized so q < 2*BQ always
    int b, r, off;
    if (q < BQ) { b = q; r = uid[q]; off = 0; }
    else { b = q - BQ; r = NUSERS + iid[q - BQ]; off = DIM; }
    int2 mv = meta2[r];
    int start = mv.x, n = mv.y;
    int n8 = (n + 7) & ~7;
    const char* base2 = (const char*)in + (dg << 4);

    v2f acc2[4] = {(v2f)0.f, (v2f)0.f, (v2f)0.f, (v2f)0.f};
    batch8(col_s, start, 0, n8, eslot, base2, acc2);
    if (__any(n8 > 32))
        batch8(col_s, start, 32, n8, eslot, base2, acc2);
    if (__any(n8 > 64)) {
        for (int i = 64 + eslot; i < n8; i += 4) {
            int c = col_s[start + i];
            uint4 u = *(const uint4*)(base2 + (((u32)c) << 7));
            add8p(acc2, u);
        }
    }
    reduce_half(acc2);
    if (eslot == 0) {
        float dr = (n > 0) ? (1.0f / sqrtf((float)n)) : 0.0f;   // dis[r]
        float* o = out + (size_t)b * (2 * DIM) + off + dg * 8;
#pragma unroll
        for (int j = 0; j < 4; ++j) {
            o[2 * j]     = (o[2 * j]     + dr * acc2[j].x) * 0.25f;
            o[2 * j + 1] = (o[2 * j + 1] + dr * acc2[j].y) * 0.25f;
        }
    }
}

// ---------------- init: bin cursors, m2 mask, sentinel rows ----------------
__global__ void k_init(int* __restrict__ bin_cur, u32* __restrict__ m2w,
                       u16* __restrict__ ea, u16* __restrict__ eb) {
    int t = blockIdx.x * blockDim.x + threadIdx.x;
    if (t < NBIN) bin_cur[t] = t * BINCAP;
    if (t < 37504) m2w[t] = 0;                 // zero 150016 bytes of m2
    if (t < 32) {                              // zero sentinel row NN in both tables
        ((u32*)(ea + (size_t)NN * DIM))[t] = 0;
        ((u32*)(eb + (size_t)NN * DIM))[t] = 0;
    }
}

// ---------------- Pass A: block-local counting sort, coalesced flush -------
// 1024 threads, 12K edges/block: histogram by bin -> 1024-wide scan -> reserve
// global chunk per bin -> scatter packed edges into LDS ordered by bin ->
// wave-cooperative flush. Packed u32: (row&255)<<24 | col  (col < 2^24)
__global__ void __launch_bounds__(1024) k_binA2(
        const int* __restrict__ row, const int* __restrict__ col,
        int* __restrict__ bin_cur, u32* __restrict__ pairs, int E) {
    __shared__ u32 stage[EPB2];            // 48 KB
    __shared__ int hist[NBIN];
    __shared__ int base_l[NBIN];
    __shared__ int cbase[NBIN];
    __shared__ int lcur[NBIN];
    __shared__ int s[1024];
    int t = threadIdx.x;
    int base = blockIdx.x * EPB2;
    int lim = min(E - base, EPB2);
    int n4 = lim >> 2;

    if (t < NBIN) hist[t] = 0;
    __syncthreads();

    // P1: histogram by bin (int4-vectorized)
    for (int i = t; i < n4; i += 1024) {
        int4 r4 = ((const int4*)(row + base))[i];
        atomicAdd(&hist[r4.x >> 8], 1);
        atomicAdd(&hist[r4.y >> 8], 1);
        atomicAdd(&hist[r4.z >> 8], 1);
        atomicAdd(&hist[r4.w >> 8], 1);
    }
    for (int i = (n4 << 2) + t; i < lim; i += 1024)
        atomicAdd(&hist[row[base + i] >> 8], 1);
    __syncthreads();

    // P2: 1024-wide exclusive scan of hist + per-bin global chunk reserve
    int v = (t < NBIN) ? hist[t] : 0;
    s[t] = v;
    __syncthreads();
    for (int off = 1; off < 1024; off <<= 1) {
        int x = (t >= off) ? s[t - off] : 0;
        __syncthreads();
        s[t] += x;
        __syncthreads();
    }
    if (t < NBIN) {
        int excl = s[t] - v;
        base_l[t] = excl;
        lcur[t] = excl;
        cbase[t] = (v > 0) ? atomicAdd(&bin_cur[t], v) : 0;
    }
    __syncthreads();

    // P3: re-read edges (L2-hot, int4), scatter into LDS stage ordered by bin
    for (int i = t; i < n4; i += 1024) {
        int4 r4 = ((const int4*)(row + base))[i];
        int4 c4 = ((const int4*)(col + base))[i];
        int pos;
        pos = atomicAdd(&lcur[r4.x >> 8], 1);
        stage[pos] = ((u32)(r4.x & 255) << 24) | (u32)c4.x;
        pos = atomicAdd(&lcur[r4.y >> 8], 1);
        stage[pos] = ((u32)(r4.y & 255) << 24) | (u32)c4.y;
        pos = atomicAdd(&lcur[r4.z >> 8], 1);
        stage[pos] = ((u32)(r4.z & 255) << 24) | (u32)c4.z;
        pos = atomicAdd(&lcur[r4.w >> 8], 1);
        stage[pos] = ((u32)(r4.w & 255) << 24) | (u32)c4.w;
    }
    for (int i = (n4 << 2) + t; i < lim; i += 1024) {
        int r = row[base + i];
        int c = col[base + i];
        int pos = atomicAdd(&lcur[r >> 8], 1);
        stage[pos] = ((u32)(r & 255) << 24) | (u32)c;
    }
    __syncthreads();

    // P4: wave-cooperative flush, one bin per wave (coalesced stores)
    int wv = t >> 6;
    int lane = t & 63;
    for (int b = wv; b < NBIN; b += 16) {
        int h = hist[b];
        int lb = base_l[b];
        size_t gb = (size_t)cbase[b];
        for (int i = lane; i < h; i += 64)
            pairs[gb + i] = stage[lb + i];
    }
}

// ---------------- Pass B: per-bin row sort; derives rs/deg/meta2; pads to 8 ----
__global__ void __launch_bounds__(1024) k_binB(
        const u32* __restrict__ pairs, const int* __restrict__ bin_cur,
        int* __restrict__ col_s, int* __restrict__ rs, int* __restrict__ deg,
        int2* __restrict__ meta2) {
    __shared__ int cnt[256];
    __shared__ int pscan[256];
    __shared__ int cur[256];
    int b = blockIdx.x;
    int t = threadIdx.x;
    int base = b * BINCAP;
    int end = bin_cur[b];
    int cnt4 = (end - base) >> 2;
    if (t < 256) cnt[t] = 0;
    __syncthreads();
    for (int i = t; i < cnt4; i += 1024) {
        uint4 p4 = ((const uint4*)(pairs + base))[i];
        atomicAdd(&cnt[p4.x >> 24], 1);
        atomicAdd(&cnt[p4.y >> 24], 1);
        atomicAdd(&cnt[p4.z >> 24], 1);
        atomicAdd(&cnt[p4.w >> 24], 1);
    }
    for (int i = base + (cnt4 << 2) + t; i < end; i += 1024)
        atomicAdd(&cnt[pairs[i] >> 24], 1);
    __syncthreads();
    int v = (t < 256) ? cnt[t] : 0;
    int pv = (v + 7) & ~7;                    // row segment padded to multiple of 8
    if (t < 256) pscan[t] = pv;
    __syncthreads();
    for (int off = 1; off < 256; off <<= 1) {
        int x = (t >= off && t < 256) ? pscan[t - off] : 0;
        __syncthreads();
        if (t < 256) pscan[t] += x;
        __syncthreads();
    }
    if (t < 256) {
        int rowstart = base + pscan[t] - pv;
        int r = (b << 8) + t;
        if (r < NN) {
            rs[r] = rowstart;
            deg[r] = v;
            meta2[r] = make_int2(rowstart, v);
        }
        cur[t] = rowstart;
        for (int i = v; i < pv; ++i) col_s[rowstart + i] = NN;   // sentinel pads
    }
    __syncthreads();
    for (int i = t; i < cnt4; i += 1024) {
        uint4 p4 = ((const uint4*)(pairs + base))[i];
        int pos;
        pos = atomicAdd(&cur[p4.x >> 24], 1);
        col_s[pos] = (int)(p4.x & 0x00FFFFFFu);
        pos = atomicAdd(&cur[p4.y >> 24], 1);
        col_s[pos] = (int)(p4.y & 0x00FFFFFFu);
        pos = atomicAdd(&cur[p4.z >> 24], 1);
        col_s[pos] = (int)(p4.z & 0x00FFFFFFu);
        pos = atomicAdd(&cur[p4.w >> 24], 1);
        col_s[pos] = (int)(p4.w & 0x00FFFFFFu);
    }
    for (int i = base + (cnt4 << 2) + t; i < end; i += 1024) {
        u32 p = pairs[i];
        int pos = atomicAdd(&cur[p >> 24], 1);
        col_s[pos] = (int)(p & 0x00FFFFFFu);
    }
}

// ---------------- t0 = dis ⊙ emb0, bf16 ----------------
__global__ void k_concat_t0(const float* __restrict__ u, const float* __restrict__ it,
                            const int* __restrict__ deg, u16* __restrict__ emb) {
    int i = blockIdx.x * blockDim.x + threadIdx.x;   // ushort4 index (4 dims), 16/row
    const int NU4 = NUSERS * DIM / 4;
    const int NT4 = NN * DIM / 4;
    if (i >= NT4) return;
    int row = i >> 4;
    int d = deg[row];
    float sc = (d > 0) ? (1.0f / sqrtf((float)d)) : 0.0f;
    float4 v = (i < NU4) ? ((const float4*)u)[i] : ((const float4*)it)[i - NU4];
    ushort4 o;
    o.x = f2bf(sc * v.x); o.y = f2bf(sc * v.y);
    o.z = f2bf(sc * v.z); o.w = f2bf(sc * v.w);
    ((ushort4*)emb)[i] = o;
}

// mark rows needed for hop-2 output: one wave per query row, lanes scatter
__global__ void k_mark(const int* __restrict__ uid, const int* __restrict__ iid,
                       const int* __restrict__ rs, const int* __restrict__ deg,
                       const int* __restrict__ col_s, unsigned char* __restrict__ m2) {
    int q = (blockIdx.x * blockDim.x + threadIdx.x) >> 6;
    if (q >= 2 * BQ) return;
    int lane = threadIdx.x & 63;
    int r = (q < BQ) ? uid[q] : (NUSERS + iid[q - BQ]);
    if (lane == 0) m2[r] = 1;
    int s = rs[r], n = deg[r];
    for (int i = lane; i < n; i += 64) m2[col_s[s + i]] = 1;
}

// ---------------- output gathers ----------------

__global__ void k_gather_init(const int* __restrict__ uid, const int* __restrict__ iid,
                              const float* __restrict__ u, const float* __restrict__ it,
                              float* __restrict__ out) {
    int t = blockIdx.x * blockDim.x + threadIdx.x;
    if (t >= BQ * DIM) return;
    int b = t >> 6;
    int d = t & 63;
    out[b * (2 * DIM) + d]       = u[(size_t)uid[b] * DIM + d];
    out[b * (2 * DIM) + DIM + d] = it[(size_t)iid[b] * DIM + d];
}

// out += sqrt(deg[r]) * t_k[r]   (emb_k = rdis ⊙ t_k)
__global__ void k_gather_add(const int* __restrict__ uid, const int* __restrict__ iid,
                             const int* __restrict__ deg, const u16* __restrict__ emb,
                             float* __restrict__ out) {
    int t = blockIdx.x * blockDim.x + threadIdx.x;
    if (t >= BQ * DIM) return;
    int b = t >> 6;
    int d = t & 63;
    int ru = uid[b];
    int ri = NUSERS + iid[b];
    int du = deg[ru], di = deg[ri];
    float su = (du > 0) ? sqrtf((float)du) : 0.0f;
    float si = (di > 0) ? sqrtf((float)di) : 0.0f;
    int ou = b * (2 * DIM) + d;
    int oi = ou + DIM;
    out[ou] = out[ou] + su * bf2f(emb[(size_t)ru * DIM + d]);
    out[oi] = out[oi] + si * bf2f(emb[(size_t)ri * DIM + d]);
}

// ---------------- launch ----------------

extern "C" void kernel_launch(void* const* d_in, const int* in_sizes, int n_in,
                              void* d_out, int out_size, void* d_ws, size_t ws_size,
                              hipStream_t stream) {
    const float* users_emb = (const float*)d_in[0];
    const float* items_emb = (const float*)d_in[1];
    const int*   edge_row  = (const int*)d_in[2];
    const int*   edge_col  = (const int*)d_in[3];
    const int*   user_id   = (const int*)d_in[4];
    const int*   item_ids  = (const int*)d_in[5];
    float* out = (float*)d_out;

    char* ws = (char*)d_ws;
    // byte layout (ends ~90.3 MB):
    int*   deg_i   = (int*)  (ws + 0);          // 600 KB
    int*   rs      = (int*)  (ws + 655360);     // 600 KB
    int*   bin_cur = (int*)  (ws + 1310720);    // 2.4 KB
    unsigned char* m2 = (unsigned char*)(ws + 1400000);  // 150 KB
    int2*  meta2   = (int2*) (ws + 2097152);    // 1.2 MB
    int*   col_s   = (int*)  (ws + 4194304);    // 586*9216*4 = 21.6 MB
    u32*   pairs   = (u32*)  (ws + 29360128);   // 21.6 MB
    u16*   emb_a   = (u16*)  (ws + 54525952);   // (NN+1)*64*2 = 19.2 MB
    u16*   emb_b   = (u16*)  (ws + 75497472);   // 19.2 MB

    // init cursors + m2 + sentinel rows
    k_init<<<147, 256, 0, stream>>>(bin_cur, (u32*)m2, emb_a, emb_b);

    // binned CSR build (counting-sort pass A; pass B derives deg/rs/meta2)
    k_binA2<<<(NE + EPB2 - 1) / EPB2, 1024, 0, stream>>>(edge_row, edge_col, bin_cur,
                                                         pairs, NE);
    k_binB<<<NBIN, 1024, 0, stream>>>(pairs, bin_cur, col_s, rs, deg_i, meta2);

    // t0 table (bf16, dis-folded)
    k_concat_t0<<<(NN * DIM / 4 + 255) / 256, 256, 0, stream>>>(users_emb, items_emb,
                                                                deg_i, emb_a);

    // layer-0 contribution (fp32 sources)
    k_gather_init<<<(BQ * DIM + 255) / 256, 256, 0, stream>>>(user_id, item_ids,
                                                              users_emb, items_emb, out);

    // mark rows whose hop-2 output is read (one wave per query row)
    k_mark<<<(2 * BQ + 3) / 4, 256, 0, stream>>>(user_id, item_ids, rs, deg_i, col_s, m2);

    // hops: 2 rows per wave, 4 waves per block -> NN/2/4 = 18750 blocks exactly
    // hop 1: full
    k_spmm2<false><<<18750, 256, 0, stream>>>(meta2, col_s, emb_a, emb_b,
                                              (const unsigned char*)nullptr);
    k_gather_add<<<(BQ * DIM + 255) / 256, 256, 0, stream>>>(user_id, item_ids, deg_i,
                                                             emb_b, out);
    // hop 2: masked
    k_spmm2<true><<<18750, 256, 0, stream>>>(meta2, col_s, emb_b, emb_a, m2);
    k_gather_add<<<(BQ * DIM + 255) / 256, 256, 0, stream>>>(user_id, item_ids, deg_i,
                                                             emb_a, out);
    // hop 3: fused into output, fp32 accumulate, final /4 (2*BQ/2/4 = 1024 blocks)
    k_spmm_out2<<<1024, 256, 0, stream>>>(meta2, col_s, emb_a, user_id, item_ids, out);
}